// Round 1
// baseline (3056.426 us; speedup 1.0000x reference)
//
#include <hip/hip_runtime.h>

// Problem dims: BS=256, T=100, DZ=DA=32, K=3, H=128. All fp32.
static constexpr int TT = 100;
static constexpr int NB = 256;

// ---- output offsets (floats), reference return order ----
static constexpr size_t O_ML = 0;          // means[-1]      [256,32]
static constexpr size_t O_CL = 8192;       // covs[-1]       [256,32,32]
static constexpr size_t O_ME = 270336;     // means          [100,256,32]
static constexpr size_t O_CO = 1089536;    // covs           [100,256,32,32]
static constexpr size_t O_NM = 27303936;   // next_means     [100,256,32]
static constexpr size_t O_NC = 28123136;   // next_covs      [100,256,32,32]
static constexpr size_t O_AB = 54337536;   // A_bl           [256,100,32,32]
static constexpr size_t O_CB = 80551936;   // C_bl           [256,100,32,32]
static constexpr size_t O_AL = 106766336;  // alpha_bl       [256,100,3]

// ---- workspace layout (floats); needs ~856 KB of d_ws ----
static constexpr int WS_WT0 = 0;       // [40][512][4]  = concat(W_ih0,W_hh0) transposed+tiled
static constexpr int WS_WT1 = 81920;   // [64][512][4]  = concat(W_ih1,W_hh1) transposed+tiled
static constexpr int WS_B0  = 212992;  // [512] b_ih0+b_hh0
static constexpr int WS_B1  = 213504;  // [512] b_ih1+b_hh1

// =====================================================================
// Kernel 1: pack weights into k-major float4 tiles for coalesced GEMV
// =====================================================================
__global__ __launch_bounds__(256) void pack_kernel(
    const float* __restrict__ Wih0, const float* __restrict__ Whh0,
    const float* __restrict__ bih0, const float* __restrict__ bhh0,
    const float* __restrict__ Wih1, const float* __restrict__ Whh1,
    const float* __restrict__ bih1, const float* __restrict__ bhh1,
    float* __restrict__ ws)
{
  int idx = blockIdx.x * 256 + threadIdx.x;
  if (idx < 81920) {
    int kb = idx >> 11, rem = idx & 2047;
    int j = rem >> 2, c = rem & 3;
    int k = kb * 4 + c;  // 0..159 : [x(32) | h0(128)]
    ws[WS_WT0 + idx] = (k < 32) ? Wih0[j * 32 + k] : Whh0[j * 128 + (k - 32)];
  } else if (idx < 212992) {
    int d = idx - 81920;
    int kb = d >> 11, rem = d & 2047;
    int j = rem >> 2, c = rem & 3;
    int k = kb * 4 + c;  // 0..255 : [h0(128) | h1(128)]
    ws[WS_WT1 + d] = (k < 128) ? Wih1[j * 128 + k] : Whh1[j * 128 + (k - 128)];
  } else if (idx < 213504) {
    int j = idx - 212992;
    ws[WS_B0 + j] = bih0[j] + bhh0[j];
  } else if (idx < 214016) {
    int j = idx - 213504;
    ws[WS_B1 + j] = bih1[j] + bhh1[j];
  }
}

// =====================================================================
// Kernel 2: 2-layer LSTM + softmax head. 128 WGs x 512 thr, 2 batch/WG.
// Thread j owns gate-row j (of 512); xh vectors broadcast from LDS.
// =====================================================================
__device__ __forceinline__ float sigf(float x) { return 1.0f / (1.0f + expf(-x)); }
__device__ __forceinline__ float dot4(float4 w, float4 x, float acc) {
  acc = fmaf(w.x, x.x, acc); acc = fmaf(w.y, x.y, acc);
  acc = fmaf(w.z, x.z, acc); acc = fmaf(w.w, x.w, acc);
  return acc;
}

__global__ __launch_bounds__(512) void lstm_kernel(
    const float* __restrict__ a, const float* __restrict__ a0,
    const float* __restrict__ ws,
    const float* __restrict__ Wlin, const float* __restrict__ blin,
    float* __restrict__ alpha_out)
{
  __shared__ __align__(16) float xh0[2][160];  // [x_t(32) | h0(128)]
  __shared__ __align__(16) float xh1[2][256];  // [h0(128) | h1(128)]
  __shared__ float c0s[2][128], c1s[2][128];
  __shared__ float g0[2][512], g1[2][512];
  __shared__ float bs0[512], bs1[512];
  __shared__ float wlin_s[384], blin_s[3];
  __shared__ float red[2][3][16], lgt[2][3];

  const float4* WT0 = (const float4*)(ws + WS_WT0);
  const float4* WT1 = (const float4*)(ws + WS_WT1);
  const int tid = threadIdx.x;
  const int wg = blockIdx.x;

  bs0[tid] = ws[WS_B0 + tid];
  bs1[tid] = ws[WS_B1 + tid];
  if (tid < 384) wlin_s[tid] = Wlin[tid];
  if (tid < 3) blin_s[tid] = blin[tid];
  if (tid < 128) {
#pragma unroll
    for (int bb = 0; bb < 2; ++bb) {
      xh0[bb][32 + tid] = 0.0f;
      xh1[bb][tid] = 0.0f;
      xh1[bb][128 + tid] = 0.0f;
      c0s[bb][tid] = 0.0f;
      c1s[bb][tid] = 0.0f;
    }
  }
  __syncthreads();

  for (int t = 0; t < TT; ++t) {
    // x_t = (t==0) ? a0 : a[b][t-1]
    if (tid < 64) {
      int bb = tid >> 5, k = tid & 31;
      xh0[bb][k] = (t == 0) ? a0[k]
                            : a[((size_t)(2 * wg + bb) * TT + (t - 1)) * 32 + k];
    }
    __syncthreads();
    // layer 0 gates: [512] = W0cat[512x160] @ xh0
    {
      float acc0 = bs0[tid], acc1 = acc0;
#pragma unroll 8
      for (int kb = 0; kb < 40; ++kb) {
        float4 w = WT0[kb * 512 + tid];
        float4 x0 = *(const float4*)&xh0[0][kb * 4];
        float4 x1 = *(const float4*)&xh0[1][kb * 4];
        acc0 = dot4(w, x0, acc0);
        acc1 = dot4(w, x1, acc1);
      }
      g0[0][tid] = acc0;
      g0[1][tid] = acc1;
    }
    __syncthreads();
    if (tid < 256) {  // combine layer0 (gate order i,f,g,o)
      int bb = tid >> 7, u = tid & 127;
      float ig = sigf(g0[bb][u]);
      float fg = sigf(g0[bb][128 + u]);
      float gg = tanhf(g0[bb][256 + u]);
      float og = sigf(g0[bb][384 + u]);
      float c = fmaf(fg, c0s[bb][u], ig * gg);
      float h = og * tanhf(c);
      c0s[bb][u] = c;
      xh0[bb][32 + u] = h;
      xh1[bb][u] = h;
    }
    __syncthreads();
    // layer 1 gates
    {
      float acc0 = bs1[tid], acc1 = acc0;
#pragma unroll 8
      for (int kb = 0; kb < 64; ++kb) {
        float4 w = WT1[kb * 512 + tid];
        float4 x0 = *(const float4*)&xh1[0][kb * 4];
        float4 x1 = *(const float4*)&xh1[1][kb * 4];
        acc0 = dot4(w, x0, acc0);
        acc1 = dot4(w, x1, acc1);
      }
      g1[0][tid] = acc0;
      g1[1][tid] = acc1;
    }
    __syncthreads();
    if (tid < 256) {  // combine layer1
      int bb = tid >> 7, u = tid & 127;
      float ig = sigf(g1[bb][u]);
      float fg = sigf(g1[bb][128 + u]);
      float gg = tanhf(g1[bb][256 + u]);
      float og = sigf(g1[bb][384 + u]);
      float c = fmaf(fg, c1s[bb][u], ig * gg);
      float h = og * tanhf(c);
      c1s[bb][u] = c;
      xh1[bb][128 + u] = h;
    }
    __syncthreads();
    // logits = W_lin @ h1 : parallel partials then tiny reduce
    if (tid < 96) {
      int bb = tid / 48, rr = tid % 48;
      int k = rr >> 4, l = rr & 15;
      float p = 0.0f;
#pragma unroll
      for (int c = 0; c < 8; ++c)
        p = fmaf(wlin_s[k * 128 + l * 8 + c], xh1[bb][128 + l * 8 + c], p);
      red[bb][k][l] = p;
    }
    __syncthreads();
    if (tid < 6) {
      int bb = tid / 3, k = tid % 3;
      float s = blin_s[k];
#pragma unroll
      for (int l = 0; l < 16; ++l) s += red[bb][k][l];
      lgt[bb][k] = s;
    }
    __syncthreads();
    if (tid < 2) {  // softmax over K=3, write alpha_bl [bs][T][3]
      float l0 = lgt[tid][0], l1 = lgt[tid][1], l2 = lgt[tid][2];
      float mx = fmaxf(l0, fmaxf(l1, l2));
      float e0 = expf(l0 - mx), e1 = expf(l1 - mx), e2 = expf(l2 - mx);
      float inv = 1.0f / (e0 + e1 + e2);
      size_t base = ((size_t)(2 * wg + tid) * TT + t) * 3;
      alpha_out[base + 0] = e0 * inv;
      alpha_out[base + 1] = e1 * inv;
      alpha_out[base + 2] = e2 * inv;
    }
    __syncthreads();
  }
}

// =====================================================================
// Kernel 3: Kalman filter. 256 WGs (1 per batch) x 256 thr.
// Sigma_post = Sp - M^T (S^{-1} M), M = C*Sp.  Cholesky + 2 solves done
// register-resident on lanes 0..31 (readlane broadcasts, no barriers).
// =====================================================================
__device__ __forceinline__ float rl(float x, int lane) {
  return __uint_as_float(
      (unsigned)__builtin_amdgcn_readlane((int)__float_as_uint(x), lane));
}

__global__ __launch_bounds__(256) void kf_kernel(
    const float* __restrict__ a, const float* __restrict__ Ag,
    const float* __restrict__ Cg, const float* __restrict__ alpha,
    float* __restrict__ out)
{
  __shared__ float As[3][1024], Cs[3][1024];
  __shared__ float An[32][33], Ct[32][33], Sp[32][33], Mm[32][33];
  __shared__ float Ss[32][33], Tm[32][33], Xx[32][33];
  __shared__ float mu_s[32], mup_s[32], al_s[3], aln_s[3];

  const int tid = threadIdx.x;
  const int b = blockIdx.x;

  for (int q = tid; q < 3072; q += 256) {
    (&As[0][0])[q] = Ag[q];
    (&Cs[0][0])[q] = Cg[q];
  }
#pragma unroll
  for (int q = 0; q < 4; ++q) {
    int e = tid + 256 * q, i = e >> 5, j = e & 31;
    Sp[i][j] = (i == j) ? 1.0f : 0.0f;  // sigma0 = I
  }
  if (tid < 32) { mu_s[tid] = 0.0f; mup_s[tid] = 0.0f; }
  __syncthreads();

  float* means_g  = out + O_ME;
  float* covs_g   = out + O_CO;
  float* nmeans_g = out + O_NM;
  float* ncovs_g  = out + O_NC;
  float* Abl_g    = out + O_AB;
  float* Cbl_g    = out + O_CB;

  for (int t = 0; t < TT; ++t) {
    if (tid < 3) {
      al_s[tid] = alpha[((size_t)b * TT + t) * 3 + tid];
    } else if (tid < 6) {
      int tn = (t < TT - 1) ? t + 1 : TT - 1;
      aln_s[tid - 3] = alpha[((size_t)b * TT + tn) * 3 + (tid - 3)];
    }
    __syncthreads();
    // mixtures: A_cur (output), A_next (transition), C_t
#pragma unroll
    for (int q = 0; q < 4; ++q) {
      int e = tid + 256 * q, i = e >> 5, j = e & 31;
      float aa = al_s[0]*As[0][e] + al_s[1]*As[1][e] + al_s[2]*As[2][e];
      float an = aln_s[0]*As[0][e] + aln_s[1]*As[1][e] + aln_s[2]*As[2][e];
      float cc = al_s[0]*Cs[0][e] + al_s[1]*Cs[1][e] + al_s[2]*Cs[2][e];
      An[i][j] = an;
      Ct[i][j] = cc;
      Abl_g[((size_t)b * TT + t) * 1024 + e] = aa;
      Cbl_g[((size_t)b * TT + t) * 1024 + e] = cc;
    }
    __syncthreads();
    if (t > 0) {  // predict with A_mix(t) (= A_next of step t-1)
#pragma unroll
      for (int q = 0; q < 4; ++q) {
        int e = tid + 256 * q, i = e >> 5, j = e & 31;
        float acc = 0.0f;
#pragma unroll
        for (int k = 0; k < 32; ++k) acc = fmaf(An[i][k], Sp[k][j], acc);
        Tm[i][j] = acc;  // A*Sigma
      }
      __syncthreads();
#pragma unroll
      for (int q = 0; q < 4; ++q) {
        int e = tid + 256 * q, i = e >> 5, j = e & 31;
        float acc = 0.0f;
#pragma unroll
        for (int k = 0; k < 32; ++k) acc = fmaf(Tm[i][k], An[j][k], acc);
        Ss[i][j] = acc;  // A*Sigma*A^T  (temp)
      }
      __syncthreads();
#pragma unroll
      for (int q = 0; q < 4; ++q) {
        int e = tid + 256 * q, i = e >> 5, j = e & 31;
        float v = 0.5f * (Ss[i][j] + Ss[j][i]);
        if (i == j) v += 1.0e-3f;  // + Q
        Sp[i][j] = v;
      }
      if (tid < 32) {  // mu_pred = A_mix(t) * mu
        float acc = 0.0f;
#pragma unroll
        for (int k = 0; k < 32; ++k) acc = fmaf(An[tid][k], mu_s[k], acc);
        mup_s[tid] = acc;
      }
      __syncthreads();
    }
    // next_means[t], next_covs[t] = predicted state entering step t
#pragma unroll
    for (int q = 0; q < 4; ++q) {
      int e = tid + 256 * q, i = e >> 5, j = e & 31;
      ncovs_g[((size_t)t * NB + b) * 1024 + e] = Sp[i][j];
    }
    if (tid < 32) nmeans_g[((size_t)t * NB + b) * 32 + tid] = mup_s[tid];
    // M = C * Sp
#pragma unroll
    for (int q = 0; q < 4; ++q) {
      int e = tid + 256 * q, i = e >> 5, j = e & 31;
      float acc = 0.0f;
#pragma unroll
      for (int k = 0; k < 32; ++k) acc = fmaf(Ct[i][k], Sp[k][j], acc);
      Mm[i][j] = acc;
    }
    __syncthreads();
    // S = M * C^T + R
#pragma unroll
    for (int q = 0; q < 4; ++q) {
      int e = tid + 256 * q, i = e >> 5, j = e & 31;
      float acc = (i == j) ? 1.0e-3f : 0.0f;
#pragma unroll
      for (int k = 0; k < 32; ++k) acc = fmaf(Mm[i][k], Ct[j][k], acc);
      Ss[i][j] = acc;
    }
    __syncthreads();
    // ---- wave-0 register Cholesky + solves: X = S^{-1} M ----
    if (tid < 32) {
      const int l = tid;
      float s[32], m[32], rinv[32];
#pragma unroll
      for (int k = 0; k < 32; ++k) { s[k] = Ss[l][k]; m[k] = Mm[k][l]; }
      // innovation r = a_t - C*mu_pred (lane l holds r[l])
      float rv = a[((size_t)b * TT + t) * 32 + l];
#pragma unroll
      for (int k = 0; k < 32; ++k) rv = fmaf(-Ct[l][k], mup_s[k], rv);
      // Cholesky (lane l = row l; column broadcast via readlane)
#pragma unroll
      for (int jj = 0; jj < 32; ++jj) {
        float sjj = rl(s[jj], jj);
        float ri = 1.0f / sqrtf(sjj);
        rinv[jj] = ri;
        float xj = s[jj] * ri;  // L[l][jj]
        s[jj] = xj;
#pragma unroll
        for (int k = jj + 1; k < 32; ++k)
          s[k] = fmaf(-xj, rl(xj, k), s[k]);  // Schur update
      }
      // forward solve L Y = M (lane l = RHS column l)
#pragma unroll
      for (int ii = 0; ii < 32; ++ii) {
        m[ii] *= rinv[ii];
        float yi = m[ii];
#pragma unroll
        for (int k = ii + 1; k < 32; ++k)
          m[k] = fmaf(-rl(s[ii], k), yi, m[k]);  // L[k][ii]
      }
      // backward solve L^T X = Y
#pragma unroll
      for (int ii = 31; ii >= 0; --ii) {
        m[ii] *= rinv[ii];
        float xi = m[ii];
#pragma unroll
        for (int k = 0; k < ii; ++k)
          m[k] = fmaf(-rl(s[k], ii), xi, m[k]);  // L[ii][k]
      }
#pragma unroll
      for (int k = 0; k < 32; ++k) Xx[k][l] = m[k];
      // mu = mu_pred + X^T r   (K = M^T S^{-1} = X^T)
      float mu = mup_s[l];
#pragma unroll
      for (int k = 0; k < 32; ++k) mu = fmaf(m[k], rl(rv, k), mu);
      mu_s[l] = mu;
      means_g[((size_t)t * NB + b) * 32 + l] = mu;
      if (t == TT - 1) out[O_ML + (size_t)b * 32 + l] = mu;
    }
    __syncthreads();
    // Sigma_post = Sp - M^T X
#pragma unroll
    for (int q = 0; q < 4; ++q) {
      int e = tid + 256 * q, i = e >> 5, j = e & 31;
      float acc = Sp[i][j];
#pragma unroll
      for (int k = 0; k < 32; ++k) acc = fmaf(-Mm[k][i], Xx[k][j], acc);
      Tm[i][j] = acc;
    }
    __syncthreads();
#pragma unroll
    for (int q = 0; q < 4; ++q) {
      int e = tid + 256 * q, i = e >> 5, j = e & 31;
      float v = 0.5f * (Tm[i][j] + Tm[j][i]);  // symmetrize
      Sp[i][j] = v;
      covs_g[((size_t)t * NB + b) * 1024 + e] = v;
      if (t == TT - 1) out[O_CL + (size_t)b * 1024 + e] = v;
    }
    __syncthreads();
  }
}

// =====================================================================
extern "C" void kernel_launch(void* const* d_in, const int* in_sizes, int n_in,
                              void* d_out, int out_size, void* d_ws, size_t ws_size,
                              hipStream_t stream) {
  const float* a    = (const float*)d_in[0];
  const float* a0   = (const float*)d_in[1];
  const float* Ag   = (const float*)d_in[2];
  const float* Cg   = (const float*)d_in[3];
  const float* Wih0 = (const float*)d_in[4];
  const float* Whh0 = (const float*)d_in[5];
  const float* bih0 = (const float*)d_in[6];
  const float* bhh0 = (const float*)d_in[7];
  const float* Wih1 = (const float*)d_in[8];
  const float* Whh1 = (const float*)d_in[9];
  const float* bih1 = (const float*)d_in[10];
  const float* bhh1 = (const float*)d_in[11];
  const float* Wlin = (const float*)d_in[12];
  const float* blin = (const float*)d_in[13];
  float* out = (float*)d_out;
  float* ws = (float*)d_ws;  // needs >= 856 KB

  pack_kernel<<<836, 256, 0, stream>>>(Wih0, Whh0, bih0, bhh0,
                                       Wih1, Whh1, bih1, bhh1, ws);
  lstm_kernel<<<128, 512, 0, stream>>>(a, a0, ws, Wlin, blin, out + O_AL);
  kf_kernel<<<256, 256, 0, stream>>>(a, Ag, Cg, out + O_AL, out);
}

// Round 2
// 2713.446 us; speedup vs baseline: 1.1264x; 1.1264x over previous
//
#include <hip/hip_runtime.h>

// Problem dims: BS=256, T=100, DZ=DA=32, K=3, H=128. All fp32.
static constexpr int TT = 100;
static constexpr int NB = 256;

// ---- output offsets (floats), reference return order ----
static constexpr size_t O_ML = 0;          // means[-1]      [256,32]
static constexpr size_t O_CL = 8192;       // covs[-1]       [256,32,32]
static constexpr size_t O_ME = 270336;     // means          [100,256,32]
static constexpr size_t O_CO = 1089536;    // covs           [100,256,32,32]
static constexpr size_t O_NM = 27303936;   // next_means     [100,256,32]
static constexpr size_t O_NC = 28123136;   // next_covs      [100,256,32,32]
static constexpr size_t O_AB = 54337536;   // A_bl           [256,100,32,32]
static constexpr size_t O_CB = 80551936;   // C_bl           [256,100,32,32]
static constexpr size_t O_AL = 106766336;  // alpha_bl       [256,100,3]

// ---- workspace layout (floats) ----
static constexpr int WS_WT0 = 0;       // [40][512][4]
static constexpr int WS_WT1 = 81920;   // [64][512][4]
static constexpr int WS_B0  = 212992;  // [512]
static constexpr int WS_B1  = 213504;  // [512]

// =====================================================================
// Kernel 1: pack weights into k-major float4 tiles for coalesced GEMV
// =====================================================================
__global__ __launch_bounds__(256) void pack_kernel(
    const float* __restrict__ Wih0, const float* __restrict__ Whh0,
    const float* __restrict__ bih0, const float* __restrict__ bhh0,
    const float* __restrict__ Wih1, const float* __restrict__ Whh1,
    const float* __restrict__ bih1, const float* __restrict__ bhh1,
    float* __restrict__ ws)
{
  int idx = blockIdx.x * 256 + threadIdx.x;
  if (idx < 81920) {
    int kb = idx >> 11, rem = idx & 2047;
    int j = rem >> 2, c = rem & 3;
    int k = kb * 4 + c;
    ws[WS_WT0 + idx] = (k < 32) ? Wih0[j * 32 + k] : Whh0[j * 128 + (k - 32)];
  } else if (idx < 212992) {
    int d = idx - 81920;
    int kb = d >> 11, rem = d & 2047;
    int j = rem >> 2, c = rem & 3;
    int k = kb * 4 + c;
    ws[WS_WT1 + d] = (k < 128) ? Wih1[j * 128 + k] : Whh1[j * 128 + (k - 128)];
  } else if (idx < 213504) {
    int j = idx - 212992;
    ws[WS_B0 + j] = bih0[j] + bhh0[j];
  } else if (idx < 214016) {
    int j = idx - 213504;
    ws[WS_B1 + j] = bih1[j] + bhh1[j];
  }
}

// =====================================================================
// Kernel 2: 2-layer LSTM + softmax head. 128 WGs x 512 thr, 2 batch/WG.
// =====================================================================
__device__ __forceinline__ float sigf(float x) { return 1.0f / (1.0f + expf(-x)); }
__device__ __forceinline__ float dot4(float4 w, float4 x, float acc) {
  acc = fmaf(w.x, x.x, acc); acc = fmaf(w.y, x.y, acc);
  acc = fmaf(w.z, x.z, acc); acc = fmaf(w.w, x.w, acc);
  return acc;
}

__global__ __launch_bounds__(512) void lstm_kernel(
    const float* __restrict__ a, const float* __restrict__ a0,
    const float* __restrict__ ws,
    const float* __restrict__ Wlin, const float* __restrict__ blin,
    float* __restrict__ alpha_out)
{
  __shared__ __align__(16) float xh0[2][160];
  __shared__ __align__(16) float xh1[2][256];
  __shared__ float c0s[2][128], c1s[2][128];
  __shared__ float g0[2][512], g1[2][512];
  __shared__ float bs0[512], bs1[512];
  __shared__ float wlin_s[384], blin_s[3];
  __shared__ float red[2][3][16], lgt[2][3];

  const float4* WT0 = (const float4*)(ws + WS_WT0);
  const float4* WT1 = (const float4*)(ws + WS_WT1);
  const int tid = threadIdx.x;
  const int wg = blockIdx.x;

  bs0[tid] = ws[WS_B0 + tid];
  bs1[tid] = ws[WS_B1 + tid];
  if (tid < 384) wlin_s[tid] = Wlin[tid];
  if (tid < 3) blin_s[tid] = blin[tid];
  if (tid < 128) {
#pragma unroll
    for (int bb = 0; bb < 2; ++bb) {
      xh0[bb][32 + tid] = 0.0f;
      xh1[bb][tid] = 0.0f;
      xh1[bb][128 + tid] = 0.0f;
      c0s[bb][tid] = 0.0f;
      c1s[bb][tid] = 0.0f;
    }
  }
  __syncthreads();

  for (int t = 0; t < TT; ++t) {
    if (tid < 64) {
      int bb = tid >> 5, k = tid & 31;
      xh0[bb][k] = (t == 0) ? a0[k]
                            : a[((size_t)(2 * wg + bb) * TT + (t - 1)) * 32 + k];
    }
    __syncthreads();
    {
      float acc0 = bs0[tid], acc1 = acc0;
#pragma unroll 8
      for (int kb = 0; kb < 40; ++kb) {
        float4 w = WT0[kb * 512 + tid];
        float4 x0 = *(const float4*)&xh0[0][kb * 4];
        float4 x1 = *(const float4*)&xh0[1][kb * 4];
        acc0 = dot4(w, x0, acc0);
        acc1 = dot4(w, x1, acc1);
      }
      g0[0][tid] = acc0;
      g0[1][tid] = acc1;
    }
    __syncthreads();
    if (tid < 256) {
      int bb = tid >> 7, u = tid & 127;
      float ig = sigf(g0[bb][u]);
      float fg = sigf(g0[bb][128 + u]);
      float gg = tanhf(g0[bb][256 + u]);
      float og = sigf(g0[bb][384 + u]);
      float c = fmaf(fg, c0s[bb][u], ig * gg);
      float h = og * tanhf(c);
      c0s[bb][u] = c;
      xh0[bb][32 + u] = h;
      xh1[bb][u] = h;
    }
    __syncthreads();
    {
      float acc0 = bs1[tid], acc1 = acc0;
#pragma unroll 8
      for (int kb = 0; kb < 64; ++kb) {
        float4 w = WT1[kb * 512 + tid];
        float4 x0 = *(const float4*)&xh1[0][kb * 4];
        float4 x1 = *(const float4*)&xh1[1][kb * 4];
        acc0 = dot4(w, x0, acc0);
        acc1 = dot4(w, x1, acc1);
      }
      g1[0][tid] = acc0;
      g1[1][tid] = acc1;
    }
    __syncthreads();
    if (tid < 256) {
      int bb = tid >> 7, u = tid & 127;
      float ig = sigf(g1[bb][u]);
      float fg = sigf(g1[bb][128 + u]);
      float gg = tanhf(g1[bb][256 + u]);
      float og = sigf(g1[bb][384 + u]);
      float c = fmaf(fg, c1s[bb][u], ig * gg);
      float h = og * tanhf(c);
      c1s[bb][u] = c;
      xh1[bb][128 + u] = h;
    }
    __syncthreads();
    if (tid < 96) {
      int bb = tid / 48, rr = tid % 48;
      int k = rr >> 4, l = rr & 15;
      float p = 0.0f;
#pragma unroll
      for (int c = 0; c < 8; ++c)
        p = fmaf(wlin_s[k * 128 + l * 8 + c], xh1[bb][128 + l * 8 + c], p);
      red[bb][k][l] = p;
    }
    __syncthreads();
    if (tid < 6) {
      int bb = tid / 3, k = tid % 3;
      float s = blin_s[k];
#pragma unroll
      for (int l = 0; l < 16; ++l) s += red[bb][k][l];
      lgt[bb][k] = s;
    }
    __syncthreads();
    if (tid < 2) {
      float l0 = lgt[tid][0], l1 = lgt[tid][1], l2 = lgt[tid][2];
      float mx = fmaxf(l0, fmaxf(l1, l2));
      float e0 = expf(l0 - mx), e1 = expf(l1 - mx), e2 = expf(l2 - mx);
      float inv = 1.0f / (e0 + e1 + e2);
      size_t base = ((size_t)(2 * wg + tid) * TT + t) * 3;
      alpha_out[base + 0] = e0 * inv;
      alpha_out[base + 1] = e1 * inv;
      alpha_out[base + 2] = e2 * inv;
    }
    __syncthreads();
  }
}

// =====================================================================
// Kernel 3: Kalman filter — ONE WAVE PER BATCH. 256 blocks x 64 threads.
// No barriers on the critical path; fused Cholesky+forward-solve;
// Sigma_post = Sp - G^T G with G = L^{-1} M (no backward solve).
// All matmuls 2x8 register-blocked with ds_read_b128 row streams.
// =====================================================================
__device__ __forceinline__ float rlf(float x, int lane) {
  return __uint_as_float(
      (unsigned)__builtin_amdgcn_readlane((int)__float_as_uint(x), lane));
}

// C-block(i0:i0+2, j0:j0+8) = A[32][36] * B[32][SB]  (row-major both)
template <int SB>
__device__ __forceinline__ void mmAB(const float* A, const float* B,
                                     int i0, int j0, float (&acc)[2][8]) {
#pragma unroll
  for (int r = 0; r < 2; ++r)
#pragma unroll
    for (int c = 0; c < 8; ++c) acc[r][c] = 0.0f;
#pragma unroll 2
  for (int kq = 0; kq < 8; ++kq) {
    float a0v[4], a1v[4];
    *(float4*)a0v = *(const float4*)(A + (i0 + 0) * 36 + 4 * kq);
    *(float4*)a1v = *(const float4*)(A + (i0 + 1) * 36 + 4 * kq);
#pragma unroll
    for (int kk = 0; kk < 4; ++kk) {
      const float* Bp = B + (4 * kq + kk) * SB + j0;
      float4 b0 = *(const float4*)Bp;
      float4 b1 = *(const float4*)(Bp + 4);
      acc[0][0] = fmaf(a0v[kk], b0.x, acc[0][0]);
      acc[0][1] = fmaf(a0v[kk], b0.y, acc[0][1]);
      acc[0][2] = fmaf(a0v[kk], b0.z, acc[0][2]);
      acc[0][3] = fmaf(a0v[kk], b0.w, acc[0][3]);
      acc[0][4] = fmaf(a0v[kk], b1.x, acc[0][4]);
      acc[0][5] = fmaf(a0v[kk], b1.y, acc[0][5]);
      acc[0][6] = fmaf(a0v[kk], b1.z, acc[0][6]);
      acc[0][7] = fmaf(a0v[kk], b1.w, acc[0][7]);
      acc[1][0] = fmaf(a1v[kk], b0.x, acc[1][0]);
      acc[1][1] = fmaf(a1v[kk], b0.y, acc[1][1]);
      acc[1][2] = fmaf(a1v[kk], b0.z, acc[1][2]);
      acc[1][3] = fmaf(a1v[kk], b0.w, acc[1][3]);
      acc[1][4] = fmaf(a1v[kk], b1.x, acc[1][4]);
      acc[1][5] = fmaf(a1v[kk], b1.y, acc[1][5]);
      acc[1][6] = fmaf(a1v[kk], b1.z, acc[1][6]);
      acc[1][7] = fmaf(a1v[kk], b1.w, acc[1][7]);
    }
  }
}

__device__ __forceinline__ void stBlock(float* M, int i0, int j0,
                                        const float (&acc)[2][8]) {
#pragma unroll
  for (int r = 0; r < 2; ++r) {
    float4 v0 = make_float4(acc[r][0], acc[r][1], acc[r][2], acc[r][3]);
    float4 v1 = make_float4(acc[r][4], acc[r][5], acc[r][6], acc[r][7]);
    *(float4*)(M + (i0 + r) * 36 + j0) = v0;
    *(float4*)(M + (i0 + r) * 36 + j0 + 4) = v1;
  }
}

__global__ __launch_bounds__(64, 1) void kf_kernel(
    const float* __restrict__ a, const float* __restrict__ Ag,
    const float* __restrict__ Cg, const float* alpha, float* out)
{
  // LDS: 24576 + 6*4608 + 3*4096 + 384 = 64896 B (<= 65536)
  __shared__ __align__(16) float As[3072], Cs[3072];
  __shared__ __align__(16) float An[32 * 36], Ct[32 * 36], Sp[32 * 36];
  __shared__ __align__(16) float TM[32 * 36], Ss[32 * 36], Gt[32 * 36];
  __shared__ __align__(16) float AnT[1024], CtT[1024], Gc[1024];
  __shared__ float muv[32], mupv[32], rv[32];

  const int l = threadIdx.x;
  const int b = blockIdx.x;
  const int i0 = 2 * (l >> 2), j0 = 8 * (l & 3);

  const float4* Ag4 = (const float4*)Ag;
  const float4* Cg4 = (const float4*)Cg;
  float4* As4 = (float4*)As;
  float4* Cs4 = (float4*)Cs;
#pragma unroll
  for (int q = 0; q < 12; ++q) {
    As4[l + 64 * q] = Ag4[l + 64 * q];
    Cs4[l + 64 * q] = Cg4[l + 64 * q];
  }
  // Sigma_prior(0) = I; mu = mu_pred = 0
#pragma unroll
  for (int r = 0; r < 2; ++r)
#pragma unroll
    for (int c = 0; c < 8; ++c)
      Sp[(i0 + r) * 36 + j0 + c] = (i0 + r == j0 + c) ? 1.0f : 0.0f;
  if (l < 32) { muv[l] = 0.0f; mupv[l] = 0.0f; }
  __syncthreads();

  float* mg  = out + O_ME;
  float* cg  = out + O_CO;
  float* nmg = out + O_NM;
  float* ncg = out + O_NC;
  float* abg = out + O_AB;
  float* cbg = out + O_CB;

  for (int t = 0; t < TT; ++t) {
    // ---- mixture with alpha[t]: A_mix (= A_bl[t], also the predict matrix
    // for the carry INTO step t), C_mix; plus transposes ----
    float al0 = alpha[((size_t)b * TT + t) * 3 + 0];
    float al1 = alpha[((size_t)b * TT + t) * 3 + 1];
    float al2 = alpha[((size_t)b * TT + t) * 3 + 2];
    {
      float4* Abl4 = (float4*)(abg + ((size_t)b * TT + t) * 1024);
      float4* Cbl4 = (float4*)(cbg + ((size_t)b * TT + t) * 1024);
#pragma unroll
      for (int q = 0; q < 4; ++q) {
        int f = l + 64 * q;
        int i = f >> 3, j4 = (f & 7) * 4;
        float4 x0 = As4[f], x1 = As4[256 + f], x2 = As4[512 + f];
        float4 av;
        av.x = al0 * x0.x + al1 * x1.x + al2 * x2.x;
        av.y = al0 * x0.y + al1 * x1.y + al2 * x2.y;
        av.z = al0 * x0.z + al1 * x1.z + al2 * x2.z;
        av.w = al0 * x0.w + al1 * x1.w + al2 * x2.w;
        float4 y0 = Cs4[f], y1 = Cs4[256 + f], y2 = Cs4[512 + f];
        float4 cv;
        cv.x = al0 * y0.x + al1 * y1.x + al2 * y2.x;
        cv.y = al0 * y0.y + al1 * y1.y + al2 * y2.y;
        cv.z = al0 * y0.z + al1 * y1.z + al2 * y2.z;
        cv.w = al0 * y0.w + al1 * y1.w + al2 * y2.w;
        *(float4*)&An[i * 36 + j4] = av;
        *(float4*)&Ct[i * 36 + j4] = cv;
        AnT[(j4 + 0) * 32 + i] = av.x;
        AnT[(j4 + 1) * 32 + i] = av.y;
        AnT[(j4 + 2) * 32 + i] = av.z;
        AnT[(j4 + 3) * 32 + i] = av.w;
        CtT[(j4 + 0) * 32 + i] = cv.x;
        CtT[(j4 + 1) * 32 + i] = cv.y;
        CtT[(j4 + 2) * 32 + i] = cv.z;
        CtT[(j4 + 3) * 32 + i] = cv.w;
        Abl4[f] = av;
        Cbl4[f] = cv;
      }
    }
    __syncthreads();

    // ---- predict: Sp = sym(A*Sigma*A^T) + Q, mup = A*mu  (A = mixture(alpha[t])) ----
    if (t > 0) {
      float acc[2][8];
      mmAB<36>(An, Sp, i0, j0, acc);   // TM = A * Sigma
      stBlock(TM, i0, j0, acc);
      __syncthreads();
      mmAB<32>(TM, AnT, i0, j0, acc);  // Ss = TM * A^T
      stBlock(Ss, i0, j0, acc);
      if (l < 32) {
        float s = 0.0f;
#pragma unroll
        for (int kq = 0; kq < 8; ++kq) {
          float4 avv = *(const float4*)&An[l * 36 + 4 * kq];
          float4 mv = *(const float4*)&muv[4 * kq];
          s += avv.x * mv.x + avv.y * mv.y + avv.z * mv.z + avv.w * mv.w;
        }
        mupv[l] = s;
      }
      __syncthreads();
#pragma unroll
      for (int r = 0; r < 2; ++r)
#pragma unroll
        for (int c = 0; c < 8; ++c) {
          float x = Ss[(i0 + r) * 36 + j0 + c];
          float xt = Ss[(j0 + c) * 36 + i0 + r];
          float v = 0.5f * (x + xt) + ((i0 + r == j0 + c) ? 1.0e-3f : 0.0f);
          Sp[(i0 + r) * 36 + j0 + c] = v;
        }
      __syncthreads();
    }

    // ---- write next_covs / next_means (prior entering step t) ----
    {
      float4* dst = (float4*)(ncg + ((size_t)t * NB + b) * 1024);
#pragma unroll
      for (int r = 0; r < 2; ++r) {
        float4 v0 = *(const float4*)&Sp[(i0 + r) * 36 + j0];
        float4 v1 = *(const float4*)&Sp[(i0 + r) * 36 + j0 + 4];
        dst[((i0 + r) * 32 + j0) >> 2] = v0;
        dst[(((i0 + r) * 32 + j0) >> 2) + 1] = v1;
      }
      if (l < 32) nmg[((size_t)t * NB + b) * 32 + l] = mupv[l];
    }

    // ---- M = C * Sp (into TM); also M^T into Gt (solver RHS) ----
    {
      float acc[2][8];
      mmAB<36>(Ct, Sp, i0, j0, acc);
      stBlock(TM, i0, j0, acc);
#pragma unroll
      for (int r = 0; r < 2; ++r)
#pragma unroll
        for (int c = 0; c < 8; ++c)
          Gt[(j0 + c) * 36 + i0 + r] = acc[r][c];
      __syncthreads();
      // ---- S = M * C^T + R (into Ss) ----
      mmAB<32>(TM, CtT, i0, j0, acc);
#pragma unroll
      for (int r = 0; r < 2; ++r)
#pragma unroll
        for (int c = 0; c < 8; ++c)
          if (i0 + r == j0 + c) acc[r][c] += 1.0e-3f;
      stBlock(Ss, i0, j0, acc);
    }
    // ---- innovation r = a_t - C*mup ----
    if (l < 32) {
      float rvv = a[((size_t)b * TT + t) * 32 + l];
#pragma unroll
      for (int kq = 0; kq < 8; ++kq) {
        float4 cvv = *(const float4*)&Ct[l * 36 + 4 * kq];
        float4 mv = *(const float4*)&mupv[4 * kq];
        rvv -= cvv.x * mv.x + cvv.y * mv.y + cvv.z * mv.z + cvv.w * mv.w;
      }
      rv[l] = rvv;
    }
    __syncthreads();

    // ---- fused Cholesky (S = LL^T) + forward solve: G = L^{-1}M, y = L^{-1}r
    // lane l<32: row l of S, column l of M. lanes>=32: duplicate r as RHS.
    float s[32], m[32];
    {
      const float* srow = Ss + (l & 31) * 36;
#pragma unroll
      for (int kq = 0; kq < 8; ++kq) {
        float4 v = *(const float4*)(srow + 4 * kq);
        s[4 * kq + 0] = v.x; s[4 * kq + 1] = v.y;
        s[4 * kq + 2] = v.z; s[4 * kq + 3] = v.w;
      }
      if (l < 32) {
        const float* mrow = Gt + l * 36;
#pragma unroll
        for (int kq = 0; kq < 8; ++kq) {
          float4 v = *(const float4*)(mrow + 4 * kq);
          m[4 * kq + 0] = v.x; m[4 * kq + 1] = v.y;
          m[4 * kq + 2] = v.z; m[4 * kq + 3] = v.w;
        }
      } else {
#pragma unroll
        for (int kq = 0; kq < 8; ++kq) {
          float4 v = *(const float4*)&rv[4 * kq];
          m[4 * kq + 0] = v.x; m[4 * kq + 1] = v.y;
          m[4 * kq + 2] = v.z; m[4 * kq + 3] = v.w;
        }
      }
    }
#pragma unroll
    for (int jj = 0; jj < 32; ++jj) {
      float sjj = rlf(s[jj], jj);
      float ri = 1.0f / sqrtf(sjj);
      float xj = s[jj] * ri;
      s[jj] = xj;
      m[jj] *= ri;
#pragma unroll
      for (int k = jj + 1; k < 32; ++k) {
        float lkj = rlf(xj, k);
        s[k] = fmaf(-xj, lkj, s[k]);
        m[k] = fmaf(-lkj, m[jj], m[k]);
      }
    }
    // store G^T (row l = column l of G) and G (col-major scatter)
    if (l < 32) {
#pragma unroll
      for (int kq = 0; kq < 8; ++kq) {
        float4 v = make_float4(m[4 * kq + 0], m[4 * kq + 1],
                               m[4 * kq + 2], m[4 * kq + 3]);
        *(float4*)&Gt[l * 36 + 4 * kq] = v;
      }
#pragma unroll
      for (int k = 0; k < 32; ++k) Gc[k * 32 + l] = m[k];
    }
    // ---- mu_post = mup + G^T y (y lives on lane 32's m[]) ----
    {
      float mu = mupv[l & 31];
#pragma unroll
      for (int k = 0; k < 32; ++k) mu = fmaf(m[k], rlf(m[k], 32), mu);
      if (l < 32) {
        muv[l] = mu;
        mg[((size_t)t * NB + b) * 32 + l] = mu;
        if (t == TT - 1) out[O_ML + (size_t)b * 32 + l] = mu;
      }
    }
    __syncthreads();

    // ---- Sigma_post = Sp - G^T G (exactly symmetric); write covs ----
    {
      float acc[2][8];
      mmAB<32>(Gt, Gc, i0, j0, acc);
      float4* dst = (float4*)(cg + ((size_t)t * NB + b) * 1024);
      float4* dstL = (float4*)(out + O_CL + (size_t)b * 1024);
#pragma unroll
      for (int r = 0; r < 2; ++r) {
        float vv[8];
#pragma unroll
        for (int c = 0; c < 8; ++c) {
          float v = Sp[(i0 + r) * 36 + j0 + c] - acc[r][c];
          Sp[(i0 + r) * 36 + j0 + c] = v;
          vv[c] = v;
        }
        float4 v0 = make_float4(vv[0], vv[1], vv[2], vv[3]);
        float4 v1 = make_float4(vv[4], vv[5], vv[6], vv[7]);
        int fi = ((i0 + r) * 32 + j0) >> 2;
        dst[fi] = v0;
        dst[fi + 1] = v1;
        if (t == TT - 1) { dstL[fi] = v0; dstL[fi + 1] = v1; }
      }
    }
    __syncthreads();
  }
}

// =====================================================================
extern "C" void kernel_launch(void* const* d_in, const int* in_sizes, int n_in,
                              void* d_out, int out_size, void* d_ws, size_t ws_size,
                              hipStream_t stream) {
  const float* a    = (const float*)d_in[0];
  const float* a0   = (const float*)d_in[1];
  const float* Ag   = (const float*)d_in[2];
  const float* Cg   = (const float*)d_in[3];
  const float* Wih0 = (const float*)d_in[4];
  const float* Whh0 = (const float*)d_in[5];
  const float* bih0 = (const float*)d_in[6];
  const float* bhh0 = (const float*)d_in[7];
  const float* Wih1 = (const float*)d_in[8];
  const float* Whh1 = (const float*)d_in[9];
  const float* bih1 = (const float*)d_in[10];
  const float* bhh1 = (const float*)d_in[11];
  const float* Wlin = (const float*)d_in[12];
  const float* blin = (const float*)d_in[13];
  float* out = (float*)d_out;
  float* ws = (float*)d_ws;

  pack_kernel<<<836, 256, 0, stream>>>(Wih0, Whh0, bih0, bhh0,
                                       Wih1, Whh1, bih1, bhh1, ws);
  lstm_kernel<<<128, 512, 0, stream>>>(a, a0, ws, Wlin, blin, out + O_AL);
  kf_kernel<<<256, 64, 0, stream>>>(a, Ag, Cg, out + O_AL, out);
}